// Round 9
// baseline (1747.391 us; speedup 1.0000x reference)
//
#include <hip/hip_runtime.h>
#include <stdint.h>

#define NN   100000
#define NE   1600000
#define NG   512
#define HID  128
#define NOUT 64
#define BK   512
#define NBUK ((NN + BK - 1) / BK)            // 196 dst-buckets of 512
#define SBK  1024
#define NB2  ((NN + SBK - 1) / SBK)          // 98 src-buckets of 1024
#define AHIST_E 4096
#define NAH  ((NE + AHIST_E - 1) / AHIST_E)  // 391
#define CHUNK 8192
#define NSC  ((NE + CHUNK - 1) / CHUNK)      // 196
#define NSP  ((NN + 511) / 512)              // 196 selfpool blocks
#define SPAN 64

typedef __bf16 bf16_t;
typedef bf16_t bf16x8 __attribute__((ext_vector_type(8)));
typedef float  f32x4  __attribute__((ext_vector_type(4)));
typedef unsigned int u32;
typedef u32 u32x4 __attribute__((ext_vector_type(4)));
typedef unsigned short u16;

struct __align__(8) EdgeT { int d, s; };

__device__ __forceinline__ u16 f2b(float f) {
    union { float f; u32 u; } v; v.f = f;
    u32 u = v.u + 0x7fffu + ((v.u >> 16) & 1u);   // RNE
    return (u16)(u >> 16);
}
__device__ __forceinline__ float blo(u32 u) {
    union { u32 u; float f; } v; v.u = u << 16; return v.f;
}
__device__ __forceinline__ float bhi(u32 u) {
    union { u32 u; float f; } v; v.u = u & 0xffff0000u; return v.f;
}

// ---------------- bucket histogram (generic key shift) ----------------
template<int SHIFT, int NB>
__global__ __launch_bounds__(256) void k_bhist(const int* __restrict__ key,
                                               int* __restrict__ bcnt) {
    __shared__ int h[NB];
    int t = threadIdx.x;
    for (int i = t; i < NB; i += 256) h[i] = 0;
    __syncthreads();
    int e0 = blockIdx.x * AHIST_E;
    int e1 = min(NE, e0 + AHIST_E);
    for (int e = e0 + t; e < e1; e += 256) atomicAdd(&h[key[e] >> SHIFT], 1);
    __syncthreads();
    for (int i = t; i < NB; i += 256) if (h[i]) atomicAdd(&bcnt[i], h[i]);
}

// ---------------- bucket scan (generic) ----------------
template<int NB>
__global__ __launch_bounds__(256) void k_bscan(const int* __restrict__ bcnt,
                                               int* __restrict__ boff, int* __restrict__ gcur,
                                               int* __restrict__ rpN) {
    __shared__ int sh[256];
    int t = threadIdx.x;
    int v = (t < NB) ? bcnt[t] : 0;
    sh[t] = v; __syncthreads();
    for (int off = 1; off < 256; off <<= 1) {
        int x = (t >= off) ? sh[t - off] : 0;
        __syncthreads();
        sh[t] += x;
        __syncthreads();
    }
    if (t < NB) { int b = sh[t] - v; boff[t] = b; gcur[t] = b; }
    if (t == 0) { boff[NB] = NE; if (rpN) rpN[0] = NE; }
}

// ---------------- dst-keyed scatter (EdgeT payload) ----------------
__global__ __launch_bounds__(256) void k_scatter(const int* __restrict__ src,
                                                 const int* __restrict__ dst,
                                                 int* __restrict__ gcur,
                                                 EdgeT* __restrict__ ebuf) {
    __shared__ int hist[NBUK], base[NBUK];
    int t = threadIdx.x;
    for (int i = t; i < NBUK; i += 256) hist[i] = 0;
    __syncthreads();
    int e0 = blockIdx.x * CHUNK;
    int e1 = min(NE, e0 + CHUNK);
    for (int e = e0 + t; e < e1; e += 256) atomicAdd(&hist[dst[e] >> 9], 1);
    __syncthreads();
    for (int i = t; i < NBUK; i += 256) {
        int h = hist[i];
        base[i] = h ? atomicAdd(&gcur[i], h) : 0;
        hist[i] = 0;
    }
    __syncthreads();
    for (int e = e0 + t; e < e1; e += 256) {
        int d = dst[e], bk = d >> 9;
        int r = atomicAdd(&hist[bk], 1);
        EdgeT p; p.d = d; p.s = src[e];
        ebuf[base[bk] + r] = p;
    }
}

// ---------------- src-keyed scatter (packed u32: s_local<<17 | d) ----------------
__global__ __launch_bounds__(256) void k_scatter2(const int* __restrict__ src,
                                                  const int* __restrict__ dst,
                                                  int* __restrict__ gcur2,
                                                  u32* __restrict__ eb2) {
    __shared__ int hist[NB2], base[NB2];
    int t = threadIdx.x;
    for (int i = t; i < NB2; i += 256) hist[i] = 0;
    __syncthreads();
    int e0 = blockIdx.x * CHUNK;
    int e1 = min(NE, e0 + CHUNK);
    for (int e = e0 + t; e < e1; e += 256) atomicAdd(&hist[src[e] >> 10], 1);
    __syncthreads();
    for (int i = t; i < NB2; i += 256) {
        int h = hist[i];
        base[i] = h ? atomicAdd(&gcur2[i], h) : 0;
        hist[i] = 0;
    }
    __syncthreads();
    for (int e = e0 + t; e < e1; e += 256) {
        int s = src[e], bk = s >> 10;
        int r = atomicAdd(&hist[bk], 1);
        eb2[base[bk] + r] = ((u32)(s & 1023) << 17) | (u32)dst[e];
    }
}

// ---------------- dst-bucket CSR: rp, dinv, cntg, col ----------------
__global__ __launch_bounds__(256) void k_bucketc(const EdgeT* __restrict__ ebuf,
                                                 const int* __restrict__ boff,
                                                 const int* __restrict__ batch,
                                                 int* __restrict__ rp, float* __restrict__ dinv,
                                                 int* __restrict__ cntg, int* __restrict__ col) {
    __shared__ int cnt[BK], pos[BK], run[BK], s2[256];
    int b = blockIdx.x, t = threadIdx.x;
    int d0 = b * BK;
    int e0 = boff[b], e1 = boff[b + 1];
    for (int i = t; i < BK; i += 256) { cnt[i] = 0; run[i] = 0; }
    __syncthreads();
    for (int e = e0 + t; e < e1; e += 256) atomicAdd(&cnt[ebuf[e].d - d0], 1);
    __syncthreads();
    for (int i = t; i < BK; i += 256) {
        int v = d0 + i;
        if (v < NN) {
            dinv[v] = rsqrtf((float)(cnt[i] + 1));
            atomicAdd(&cntg[batch[v]], 1);
        }
    }
    int c0 = cnt[2 * t], c1 = cnt[2 * t + 1];
    int s = c0 + c1; s2[t] = s; __syncthreads();
    for (int off = 1; off < 256; off <<= 1) {
        int x = (t >= off) ? s2[t - off] : 0;
        __syncthreads();
        s2[t] += x;
        __syncthreads();
    }
    int bse = s2[t] - s;
    pos[2 * t] = bse; pos[2 * t + 1] = bse + c0;
    __syncthreads();
    for (int i = t; i < BK; i += 256) {
        int v = d0 + i;
        if (v < NN) rp[v] = e0 + pos[i];
    }
    for (int e = e0 + t; e < e1; e += 256) {
        EdgeT p = ebuf[e];
        int i = p.d - d0;
        int r = atomicAdd(&run[i], 1);
        col[e0 + pos[i] + r] = p.s;
    }
}

// ---------------- fused weight prep ----------------
__global__ void k_wprep(const float* __restrict__ W1, u16* __restrict__ Wp,
                        const float* __restrict__ W2, const float* __restrict__ Wfc,
                        const float* __restrict__ b2, const float* __restrict__ bfc,
                        float* __restrict__ Wc, float* __restrict__ bc) {
    int tid = blockIdx.x * blockDim.x + threadIdx.x;
    if (tid < 2048) {
        int f = tid >> 6, l = tid & 63;
        int c = f >> 2, s = f & 3;
        int n  = (l & 15) * 8 + c;
        int k0 = s * 32 + ((l >> 4) << 3);
#pragma unroll
        for (int j = 0; j < 8; j++) Wp[tid * 8 + j] = f2b(W1[(k0 + j) * HID + n]);
    } else if (tid < 2048 + HID * NOUT) {
        int t2 = tid - 2048;
        int i = t2 >> 6, o = t2 & 63;
        float a = 0.f;
        for (int k = 0; k < HID; k++) a += W2[i * HID + k] * Wfc[k * NOUT + o];
        Wc[i * NOUT + o] = a;
    } else if (tid < 2048 + HID * NOUT + NOUT) {
        int o = tid - 2048 - HID * NOUT;
        float a = bfc[o];
        for (int k = 0; k < HID; k++) a += b2[k] * Wfc[k * NOUT + o];
        bc[o] = a;
    }
}

// ---------------- GEMM: g = bf16((X @ W1) * dinv[row]) ----------------
__global__ __launch_bounds__(256) void k_gemm(const float* __restrict__ Xf,
                                              const u16* __restrict__ Wp,
                                              const float* __restrict__ dinv,
                                              u16* __restrict__ Gout) {
    int w = threadIdx.x >> 6, l = threadIdx.x & 63;
    int r0  = blockIdx.x * 64 + w * 16;
    int l15 = l & 15, lh = l >> 4;
    int arow = r0 + l15;
    int arc  = (arow < NN) ? arow : (NN - 1);

    f32x4 acc[8];
#pragma unroll
    for (int c = 0; c < 8; c++) acc[c] = (f32x4){0.f, 0.f, 0.f, 0.f};

#pragma unroll
    for (int s = 0; s < 4; s++) {
        int k0 = s * 32 + lh * 8;
        f32x4 p0 = *(const f32x4*)(Xf + (size_t)arc * HID + k0);
        f32x4 p1 = *(const f32x4*)(Xf + (size_t)arc * HID + k0 + 4);
        union { bf16x8 v; u16 h[8]; } au;
#pragma unroll
        for (int j = 0; j < 4; j++) { au.h[j] = f2b(p0[j]); au.h[j + 4] = f2b(p1[j]); }
        bf16x8 a = au.v;
#pragma unroll
        for (int c = 0; c < 8; c++) {
            bf16x8 b = *(const bf16x8*)(Wp + ((c * 4 + s) * 64 + l) * 8);
            acc[c] = __builtin_amdgcn_mfma_f32_16x16x32_bf16(a, b, acc[c], 0, 0, 0);
        }
    }
#pragma unroll
    for (int q = 0; q < 4; q++) {
        int row = r0 + lh * 4 + q;
        if (row < NN) {
            float dv = dinv[row];
            union { u32x4 v; u16 h[8]; } pk;
#pragma unroll
            for (int c = 0; c < 8; c++) pk.h[c] = f2b(acc[c][q] * dv);
            *(u32x4*)(Gout + (size_t)row * HID + l15 * 8) = pk.v;
        }
    }
}

// ---------------- aggregation layer 1 (R6-proven shape) ----------------
// T[v] = bf16(dinv[v] * relu(dinv[v]*Sum + b1))   (pre-scaled for layer 2)
__global__ __launch_bounds__(256) void k_agg(const u16* __restrict__ g,
                                             const int* __restrict__ rp,
                                             const int* __restrict__ col,
                                             const float* __restrict__ dinv,
                                             const float* __restrict__ bias,
                                             u16* __restrict__ tout) {
    int w = threadIdx.x >> 6, l = threadIdx.x & 63;
    int v = blockIdx.x * 4 + w;
    if (v >= NN) return;
    int f0 = 2 * l;
    const u16* gl = g + f0;

    u32 u = *(const u32*)(gl + (size_t)v * HID);   // self loop
    float a0 = blo(u), a1 = bhi(u);

    int e = rp[v], end = rp[v + 1];
    while (e < end) {
        int m = end - e; if (m > 64) m = 64;
        int ci = col[e + ((l < m) ? l : 0)];
        int j = 0;
        for (; j + 16 <= m; j += 16) {
            u32 uu[16];
#pragma unroll
            for (int k = 0; k < 16; k++) {
                int idx = __shfl(ci, j + k);
                uu[k] = *(const u32*)(gl + (size_t)idx * HID);
            }
#pragma unroll
            for (int k = 0; k < 16; k++) { a0 += blo(uu[k]); a1 += bhi(uu[k]); }
        }
        for (; j + 4 <= m; j += 4) {
            u32 uu[4];
#pragma unroll
            for (int k = 0; k < 4; k++) {
                int idx = __shfl(ci, j + k);
                uu[k] = *(const u32*)(gl + (size_t)idx * HID);
            }
#pragma unroll
            for (int k = 0; k < 4; k++) { a0 += blo(uu[k]); a1 += bhi(uu[k]); }
        }
        if (j < m) {
            int r = m - j;
            u32 uu[3];
#pragma unroll
            for (int k = 0; k < 3; k++) {
                int jk = j + k; int idx = __shfl(ci, (jk < m) ? jk : j);
                uu[k] = *(const u32*)(gl + (size_t)idx * HID);
            }
#pragma unroll
            for (int k = 0; k < 3; k++) {
                float mk = (k < r) ? 1.f : 0.f;
                a0 = fmaf(mk, blo(uu[k]), a0); a1 = fmaf(mk, bhi(uu[k]), a1);
            }
        }
        e += m;
    }

    float dv = dinv[v];
    float o0 = fmaxf(a0 * dv + bias[f0],     0.f) * dv;
    float o1 = fmaxf(a1 * dv + bias[f0 + 1], 0.f) * dv;
    u32 pk = (u32)f2b(o0) | ((u32)f2b(o1) << 16);
    int l15 = l & 15;
    u32 w0 = __shfl(pk, l15 * 4 + 0);
    u32 w1 = __shfl(pk, l15 * 4 + 1);
    u32 w2 = __shfl(pk, l15 * 4 + 2);
    u32 w3 = __shfl(pk, l15 * 4 + 3);
    if (l < 16) {
        u32x4 vv = (u32x4){w0, w1, w2, w3};
        *(u32x4*)(tout + (size_t)v * HID + l * 8) = vv;
    }
}

// ---------------- edge-centric pooled layer 2 ----------------
// Block (src-bucket b, feature-quarter q): LDS table [512 graphs][32 feats] f32.
// Wave processes 2 edges at once (lanes 0-31 / 32-63).  T window (1024x256B)
// is L2-resident; output tables spill linearly, summed by k_reduce.
__global__ __launch_bounds__(256) void k_pool(const u32* __restrict__ eb2,
                                              const int* __restrict__ soff,
                                              const u16* __restrict__ t,
                                              const int* __restrict__ batch,
                                              const float* __restrict__ dinv,
                                              float* __restrict__ tblg) {
    extern __shared__ float tbl[];            // NG*32 floats = 64 KB
    int bid = blockIdx.x, b = bid >> 2, q = bid & 3;
    int tid = threadIdx.x, w = tid >> 6, l = tid & 63;
    int half = l >> 5, lf = l & 31;
    for (int i = tid; i < NG * 32; i += 256) tbl[i] = 0.f;
    __syncthreads();
    int e0 = soff[b], e1 = soff[b + 1];
    const u16* tl = t + q * 32 + lf;
    for (int base = e0 + w * 64; base < e1; base += 256) {
        int n = e1 - base; if (n > 64) n = 64;
        u32 pk = eb2[base + ((l < n) ? l : 0)];
        int j = 0;
        for (; j + 8 <= n; j += 8) {
            float dv[4]; int bg[4]; float val[4];
#pragma unroll
            for (int kk = 0; kk < 4; kk++) {
                u32 p = __shfl(pk, j + kk * 2 + half);
                int d = p & 0x1FFFF;
                int s = (b << 10) | (int)(p >> 17);
                dv[kk]  = dinv[d];
                bg[kk]  = batch[d];
                val[kk] = blo((u32)tl[(size_t)s * HID]);
            }
#pragma unroll
            for (int kk = 0; kk < 4; kk++)
                atomicAdd(&tbl[bg[kk] * 32 + lf], dv[kk] * val[kk]);
        }
        for (; j < n; j += 2) {
            int k = j + half;
            int ok = (k < n);
            u32 p = __shfl(pk, ok ? k : j);
            int d = p & 0x1FFFF;
            int s = (b << 10) | (int)(p >> 17);
            float dv = ok ? dinv[d] : 0.f;
            int bg = batch[d];
            float val = blo((u32)tl[(size_t)s * HID]);
            atomicAdd(&tbl[bg * 32 + lf], dv * val);
        }
    }
    __syncthreads();
    float* out = tblg + (size_t)bid * (NG * 32);
    for (int i = tid; i < NG * 32; i += 256) out[i] = tbl[i];
}

// ---------------- self-loop pooling: psum[batch[v]] += dinv[v]*T[v] ----------------
__global__ __launch_bounds__(256) void k_selfpool(const u16* __restrict__ t,
                                                  const int* __restrict__ batch,
                                                  const float* __restrict__ dinv,
                                                  float* __restrict__ psum) {
    __shared__ float st[SPAN * HID];
    int b = blockIdx.x, tid = threadIdx.x, w = tid >> 6, l = tid & 63;
    int n0 = b * 512, n1 = min(NN, n0 + 512);
    int gmin = batch[n0], gmax = batch[n1 - 1];
    for (int i = tid; i < SPAN * HID; i += 256) st[i] = 0.f;
    __syncthreads();
    for (int v = n0 + w; v < n1; v += 4) {
        float dv = dinv[v];
        int bg = batch[v] - gmin;
        u32 u = *(const u32*)(t + (size_t)v * HID + 2 * l);
        float x0 = blo(u) * dv, x1 = bhi(u) * dv;
        if (bg < SPAN) {
            atomicAdd(&st[bg * HID + 2 * l],     x0);
            atomicAdd(&st[bg * HID + 2 * l + 1], x1);
        } else {
            atomicAdd(&psum[(size_t)(gmin + bg) * HID + 2 * l],     x0);
            atomicAdd(&psum[(size_t)(gmin + bg) * HID + 2 * l + 1], x1);
        }
    }
    __syncthreads();
    int used = gmax - gmin + 1; if (used > SPAN) used = SPAN;
    for (int i = tid; i < used * HID; i += 256)
        atomicAdd(&psum[(size_t)gmin * HID + i], st[i]);
}

// ---------------- table reduce: psum += sum_b tbl[b] ----------------
__global__ __launch_bounds__(128) void k_reduce(const float* __restrict__ tblg,
                                                float* __restrict__ psum) {
    int g = blockIdx.x, f = threadIdx.x;
    int q = f >> 5, fl = f & 31;
    float s = 0.f;
    for (int b = 0; b < NB2; b++)
        s += tblg[(size_t)(b * 4 + q) * (NG * 32) + g * 32 + fl];
    psum[(size_t)g * HID + f] += s;
}

// ---------------- pooled FC: out = (psum/cnt) @ Wc + bc ----------------
__global__ __launch_bounds__(64) void k_fc(const float* __restrict__ psum,
                                           const int* __restrict__ cntg,
                                           const float* __restrict__ Wc,
                                           const float* __restrict__ bc,
                                           float* __restrict__ out) {
    __shared__ float pooled[HID];
    int gph = blockIdx.x, t = threadIdx.x;
    float inv = 1.f / fmaxf((float)cntg[gph], 1.f);
    for (int k = t; k < HID; k += 64) pooled[k] = psum[gph * HID + k] * inv;
    __syncthreads();
    float acc = bc[t];
    for (int k = 0; k < HID; k++) acc += pooled[k] * Wc[k * NOUT + t];
    out[gph * NOUT + t] = acc;
}

extern "C" void kernel_launch(void* const* d_in, const int* in_sizes, int n_in,
                              void* d_out, int out_size, void* d_ws, size_t ws_size,
                              hipStream_t stream) {
    const float* x     = (const float*)d_in[0];
    const int*   ei    = (const int*)d_in[1];
    const int*   batch = (const int*)d_in[3];
    const float* W1    = (const float*)d_in[4];
    const float* b1    = (const float*)d_in[5];
    const float* W2    = (const float*)d_in[6];
    const float* b2    = (const float*)d_in[7];
    const float* Wfc   = (const float*)d_in[8];
    const float* bfc   = (const float*)d_in[9];
    float* out = (float*)d_out;

    const int* src = ei;
    const int* dst = ei + NE;

    char* p = (char*)d_ws;
    auto take = [&](size_t bytes) { char* r = p; p += (bytes + 255) & ~(size_t)255; return r; };
    // zero-group (one memset covers bcnt..psum)
    int*   bcnt  = (int*)take((size_t)NBUK * 4);
    int*   bcnt2 = (int*)take((size_t)NB2 * 4);
    int*   cntg  = (int*)take((size_t)NG * 4);
    float* psum  = (float*)take((size_t)NG * HID * 4);
    size_t zspan = (size_t)((char*)psum + (size_t)NG * HID * 4 - (char*)bcnt);
    int*   boff  = (int*)take((size_t)(NBUK + 1) * 4);
    int*   gcur  = (int*)take((size_t)NBUK * 4);
    int*   soff  = (int*)take((size_t)(NB2 + 1) * 4);
    int*   gcur2 = (int*)take((size_t)NB2 * 4);
    int*   rp    = (int*)take((size_t)(NN + 1) * 4);
    float* dinv  = (float*)take((size_t)NN * 4);
    u16*   Wp1   = (u16*)take((size_t)32 * 64 * 8 * 2);
    float* Wc    = (float*)take((size_t)HID * NOUT * 4);
    float* bc    = (float*)take((size_t)NOUT * 4);
    int*   col   = (int*)take((size_t)NE * 4);
    u32*   eb2   = (u32*)take((size_t)NE * 4);
    // shared region: ebuf (CSR build) -> g (gemm/agg) -> tblg (pool/reduce)
    size_t gt_bytes = (size_t)(NB2 * 4) * (NG * 32) * 4;   // 25.69 MB >= g's 25.6 MB
    char*  gt    = take(gt_bytes);
    u16*   t     = (u16*)take((size_t)NN * HID * 2);
    EdgeT* ebuf  = (EdgeT*)gt;
    u16*   g     = (u16*)gt;
    float* tblg  = (float*)gt;

    hipMemsetAsync(bcnt, 0, zspan, stream);

    k_bhist<9, NBUK><<<NAH, 256, 0, stream>>>(dst, bcnt);
    k_bhist<10, NB2><<<NAH, 256, 0, stream>>>(src, bcnt2);
    k_bscan<NBUK><<<1, 256, 0, stream>>>(bcnt, boff, gcur, rp + NN);
    k_bscan<NB2> <<<1, 256, 0, stream>>>(bcnt2, soff, gcur2, nullptr);
    k_scatter <<<NSC, 256, 0, stream>>>(src, dst, gcur, ebuf);
    k_bucketc <<<NBUK, 256, 0, stream>>>(ebuf, boff, batch, rp, dinv, cntg, col);
    k_scatter2<<<NSC, 256, 0, stream>>>(src, dst, gcur2, eb2);
    k_wprep   <<<(2048 + HID * NOUT + NOUT + 255) / 256, 256, 0, stream>>>
              (W1, Wp1, W2, Wfc, b2, bfc, Wc, bc);

    k_gemm    <<<(NN + 63) / 64, 256, 0, stream>>>(x, Wp1, dinv, g);
    k_agg     <<<(NN + 3) / 4, 256, 0, stream>>>(g, rp, col, dinv, b1, t);
    k_pool    <<<NB2 * 4, 256, NG * 32 * sizeof(float), stream>>>(eb2, soff, t, batch, dinv, tblg);
    k_selfpool<<<NSP, 256, 0, stream>>>(t, batch, dinv, psum);
    k_reduce  <<<NG, 128, 0, stream>>>(tblg, psum);
    k_fc      <<<NG, 64, 0, stream>>>(psum, cntg, Wc, bc, out);
}

// Round 10
// 433.437 us; speedup vs baseline: 4.0315x; 4.0315x over previous
//
#include <hip/hip_runtime.h>
#include <stdint.h>

#define NN   100000
#define NE   1600000
#define NG   512
#define HID  128
#define NOUT 64
#define BK   512
#define NBUK ((NN + BK - 1) / BK)            // 196 dst-buckets of 512
#define AHIST_E 4096
#define NAH  ((NE + AHIST_E - 1) / AHIST_E)  // 391
#define CHUNK 8192
#define NSC  ((NE + CHUNK - 1) / CHUNK)      // 196
#define CHSZ ((size_t)NN * 64)               // u16 elems per feature-chunk (64 feats)
#define NGRP ((NN + 3) / 4)                  // node groups of 4

typedef __bf16 bf16_t;
typedef bf16_t bf16x8 __attribute__((ext_vector_type(8)));
typedef float  f32x4  __attribute__((ext_vector_type(4)));
typedef unsigned int u32;
typedef u32 u32x4 __attribute__((ext_vector_type(4)));
typedef unsigned short u16;

struct __align__(8) EdgeT { int d, s; };

__device__ __forceinline__ u16 f2b(float f) {
    union { float f; u32 u; } v; v.f = f;
    u32 u = v.u + 0x7fffu + ((v.u >> 16) & 1u);   // RNE
    return (u16)(u >> 16);
}
__device__ __forceinline__ float blo(u32 u) {
    union { u32 u; float f; } v; v.u = u << 16; return v.f;
}
__device__ __forceinline__ float bhi(u32 u) {
    union { u32 u; float f; } v; v.u = u & 0xffff0000u; return v.f;
}

// ---------------- CSR build, bucketed (R6-proven) ----------------
__global__ __launch_bounds__(256) void k_bhist(const int* __restrict__ dst,
                                               int* __restrict__ bcnt) {
    __shared__ int h[NBUK];
    int t = threadIdx.x;
    for (int i = t; i < NBUK; i += 256) h[i] = 0;
    __syncthreads();
    int e0 = blockIdx.x * AHIST_E;
    int e1 = min(NE, e0 + AHIST_E);
    for (int e = e0 + t; e < e1; e += 256) atomicAdd(&h[dst[e] >> 9], 1);
    __syncthreads();
    for (int i = t; i < NBUK; i += 256) if (h[i]) atomicAdd(&bcnt[i], h[i]);
}

__global__ __launch_bounds__(256) void k_bscan(const int* __restrict__ bcnt,
                                               int* __restrict__ boff, int* __restrict__ gcur,
                                               int* __restrict__ rpN) {
    __shared__ int sh[256];
    int t = threadIdx.x;
    int v = (t < NBUK) ? bcnt[t] : 0;
    sh[t] = v; __syncthreads();
    for (int off = 1; off < 256; off <<= 1) {
        int x = (t >= off) ? sh[t - off] : 0;
        __syncthreads();
        sh[t] += x;
        __syncthreads();
    }
    if (t < NBUK) { int b = sh[t] - v; boff[t] = b; gcur[t] = b; }
    if (t == 0) { boff[NBUK] = NE; rpN[0] = NE; }
}

__global__ __launch_bounds__(256) void k_scatter(const int* __restrict__ src,
                                                 const int* __restrict__ dst,
                                                 int* __restrict__ gcur,
                                                 EdgeT* __restrict__ ebuf) {
    __shared__ int hist[NBUK], base[NBUK];
    int t = threadIdx.x;
    for (int i = t; i < NBUK; i += 256) hist[i] = 0;
    __syncthreads();
    int e0 = blockIdx.x * CHUNK;
    int e1 = min(NE, e0 + CHUNK);
    for (int e = e0 + t; e < e1; e += 256) atomicAdd(&hist[dst[e] >> 9], 1);
    __syncthreads();
    for (int i = t; i < NBUK; i += 256) {
        int h = hist[i];
        base[i] = h ? atomicAdd(&gcur[i], h) : 0;
        hist[i] = 0;
    }
    __syncthreads();
    for (int e = e0 + t; e < e1; e += 256) {
        int d = dst[e], bk = d >> 9;
        int r = atomicAdd(&hist[bk], 1);
        EdgeT p; p.d = d; p.s = src[e];
        ebuf[base[bk] + r] = p;
    }
}

__global__ __launch_bounds__(256) void k_bucketc(const EdgeT* __restrict__ ebuf,
                                                 const int* __restrict__ boff,
                                                 const int* __restrict__ batch,
                                                 int* __restrict__ rp, float* __restrict__ dinv,
                                                 int* __restrict__ cntg, int* __restrict__ col) {
    __shared__ int cnt[BK], pos[BK], run[BK], s2[256];
    int b = blockIdx.x, t = threadIdx.x;
    int d0 = b * BK;
    int e0 = boff[b], e1 = boff[b + 1];
    for (int i = t; i < BK; i += 256) { cnt[i] = 0; run[i] = 0; }
    __syncthreads();
    for (int e = e0 + t; e < e1; e += 256) atomicAdd(&cnt[ebuf[e].d - d0], 1);
    __syncthreads();
    for (int i = t; i < BK; i += 256) {
        int v = d0 + i;
        if (v < NN) {
            dinv[v] = rsqrtf((float)(cnt[i] + 1));
            atomicAdd(&cntg[batch[v]], 1);
        }
    }
    int c0 = cnt[2 * t], c1 = cnt[2 * t + 1];
    int s = c0 + c1; s2[t] = s; __syncthreads();
    for (int off = 1; off < 256; off <<= 1) {
        int x = (t >= off) ? s2[t - off] : 0;
        __syncthreads();
        s2[t] += x;
        __syncthreads();
    }
    int bse = s2[t] - s;
    pos[2 * t] = bse; pos[2 * t + 1] = bse + c0;
    __syncthreads();
    for (int i = t; i < BK; i += 256) {
        int v = d0 + i;
        if (v < NN) rp[v] = e0 + pos[i];
    }
    for (int e = e0 + t; e < e1; e += 256) {
        EdgeT p = ebuf[e];
        int i = p.d - d0;
        int r = atomicAdd(&run[i], 1);
        col[e0 + pos[i] + r] = p.s;
    }
}

// ---------------- fused weight prep ----------------
__global__ void k_wprep(const float* __restrict__ W1, u16* __restrict__ Wp,
                        const float* __restrict__ W2, const float* __restrict__ Wfc,
                        const float* __restrict__ b2, const float* __restrict__ bfc,
                        float* __restrict__ Wc, float* __restrict__ bc) {
    int tid = blockIdx.x * blockDim.x + threadIdx.x;
    if (tid < 2048) {
        int f = tid >> 6, l = tid & 63;
        int c = f >> 2, s = f & 3;
        int n  = (l & 15) * 8 + c;
        int k0 = s * 32 + ((l >> 4) << 3);
#pragma unroll
        for (int j = 0; j < 8; j++) Wp[tid * 8 + j] = f2b(W1[(k0 + j) * HID + n]);
    } else if (tid < 2048 + HID * NOUT) {
        int t2 = tid - 2048;
        int i = t2 >> 6, o = t2 & 63;
        float a = 0.f;
        for (int k = 0; k < HID; k++) a += W2[i * HID + k] * Wfc[k * NOUT + o];
        Wc[i * NOUT + o] = a;
    } else if (tid < 2048 + HID * NOUT + NOUT) {
        int o = tid - 2048 - HID * NOUT;
        float a = bfc[o];
        for (int k = 0; k < HID; k++) a += b2[k] * Wfc[k * NOUT + o];
        bc[o] = a;
    }
}

// ---------------- GEMM: g = bf16((X @ W1) * dinv[row]), chunked [2][NN][64] ----
__global__ __launch_bounds__(256) void k_gemm(const float* __restrict__ Xf,
                                              const u16* __restrict__ Wp,
                                              const float* __restrict__ dinv,
                                              u16* __restrict__ Gout) {
    int w = threadIdx.x >> 6, l = threadIdx.x & 63;
    int r0  = blockIdx.x * 64 + w * 16;
    int l15 = l & 15, lh = l >> 4;
    int arow = r0 + l15;
    int arc  = (arow < NN) ? arow : (NN - 1);

    f32x4 acc[8];
#pragma unroll
    for (int c = 0; c < 8; c++) acc[c] = (f32x4){0.f, 0.f, 0.f, 0.f};

#pragma unroll
    for (int s = 0; s < 4; s++) {
        int k0 = s * 32 + lh * 8;
        f32x4 p0 = *(const f32x4*)(Xf + (size_t)arc * HID + k0);
        f32x4 p1 = *(const f32x4*)(Xf + (size_t)arc * HID + k0 + 4);
        union { bf16x8 v; u16 h[8]; } au;
#pragma unroll
        for (int j = 0; j < 4; j++) { au.h[j] = f2b(p0[j]); au.h[j + 4] = f2b(p1[j]); }
        bf16x8 a = au.v;
#pragma unroll
        for (int c = 0; c < 8; c++) {
            bf16x8 b = *(const bf16x8*)(Wp + ((c * 4 + s) * 64 + l) * 8);
            acc[c] = __builtin_amdgcn_mfma_f32_16x16x32_bf16(a, b, acc[c], 0, 0, 0);
        }
    }
    // lane l15 owns global cols [8*l15, 8*l15+8) -> chunk l15>>3, in-chunk col 8*(l15&7)
#pragma unroll
    for (int q = 0; q < 4; q++) {
        int row = r0 + lh * 4 + q;
        if (row < NN) {
            float dv = dinv[row];
            union { u32x4 v; u16 h[8]; } pk;
#pragma unroll
            for (int c = 0; c < 8; c++) pk.h[c] = f2b(acc[c][q] * dv);
            *(u32x4*)(Gout + (size_t)(l15 >> 3) * CHSZ + (size_t)row * 64 + (l15 & 7) * 8) = pk.v;
        }
    }
}

// ---------------- aggregation: 2-way feature split, XCD-parity aligned ----------
// chunk = blockIdx&1 (even XCDs -> chunk0, odd -> chunk1; each XCD re-reads only
// its 12.8MB half).  Wave load = 2 rows x 128B (lanes 0-31 edge i, 32-63 edge i+1);
// per 16 edges: 8 loads + 8 shfls (half of R6's walk cost per chunk).
// LAYER 1: T[v] = bf16(dinv*relu(dinv*Sum + b1));  LAYER 2: psum[batch[v]] += dinv*Sum.
template<int LAYER>
__global__ __launch_bounds__(256) void k_agg(const u16* __restrict__ gc,
                                             const int* __restrict__ rp,
                                             const int* __restrict__ col,
                                             const float* __restrict__ dinv,
                                             const float* __restrict__ bias,
                                             u16* __restrict__ tout,
                                             const int* __restrict__ batch,
                                             float* __restrict__ psum) {
    int bid = blockIdx.x;
    int c = bid & 1;
    int w = threadIdx.x >> 6, l = threadIdx.x & 63;
    int v = (bid >> 1) * 4 + w;
    if (v >= NN) return;
    int half = l >> 5, lf = l & 31;
    const u16* gch = gc + (size_t)c * CHSZ;
    const u16* gl  = gch + 2 * lf;        // lane's 4B within any 128B chunk-row

    float a0 = 0.f, a1 = 0.f;

    int e = rp[v], end = rp[v + 1];
    while (e < end) {
        int m = end - e; if (m > 64) m = 64;
        int ci = col[e + ((l < m) ? l : 0)];
        int j = 0;
        for (; j + 16 <= m; j += 16) {
            u32 uu[8];
#pragma unroll
            for (int k = 0; k < 8; k++) {
                int idx = __shfl(ci, j + 2 * k + half);
                uu[k] = *(const u32*)(gl + (size_t)idx * 64);
            }
#pragma unroll
            for (int k = 0; k < 8; k++) { a0 += blo(uu[k]); a1 += bhi(uu[k]); }
        }
        for (; j + 2 <= m; j += 2) {
            int idx = __shfl(ci, j + half);
            u32 u0 = *(const u32*)(gl + (size_t)idx * 64);
            a0 += blo(u0); a1 += bhi(u0);
        }
        if (j < m) {                       // odd leftover: low half only
            int idx = __shfl(ci, j);
            u32 u0 = *(const u32*)(gl + (size_t)idx * 64);
            float mk = (half == 0) ? 1.f : 0.f;
            a0 = fmaf(mk, blo(u0), a0); a1 = fmaf(mk, bhi(u0), a1);
        }
        e += m;
    }

    // cross-half reduce (both halves accumulated disjoint edge subsets)
    a0 += __shfl_xor(a0, 32);
    a1 += __shfl_xor(a1, 32);

    // self loop once, post-reduce
    u32 su = *(const u32*)(gl + (size_t)v * 64);
    a0 += blo(su); a1 += bhi(su);

    float dv = dinv[v];
    int f0 = c * 64 + 2 * lf;
    if (LAYER == 1) {
        float o0 = fmaxf(a0 * dv + bias[f0],     0.f) * dv;
        float o1 = fmaxf(a1 * dv + bias[f0 + 1], 0.f) * dv;
        if (half == 0) {
            u32 pk = (u32)f2b(o0) | ((u32)f2b(o1) << 16);
            *(u32*)(tout + (size_t)c * CHSZ + (size_t)v * 64 + 2 * lf) = pk;
        }
    } else {
        if (half == 0) {
            int bg = batch[v];
            atomicAdd(&psum[(size_t)bg * HID + f0],     a0 * dv);
            atomicAdd(&psum[(size_t)bg * HID + f0 + 1], a1 * dv);
        }
    }
}

// ---------------- pooled FC: out = (psum/cnt) @ Wc + bc ----------------
__global__ __launch_bounds__(64) void k_fc(const float* __restrict__ psum,
                                           const int* __restrict__ cntg,
                                           const float* __restrict__ Wc,
                                           const float* __restrict__ bc,
                                           float* __restrict__ out) {
    __shared__ float pooled[HID];
    int gph = blockIdx.x, t = threadIdx.x;
    float inv = 1.f / fmaxf((float)cntg[gph], 1.f);
    for (int k = t; k < HID; k += 64) pooled[k] = psum[gph * HID + k] * inv;
    __syncthreads();
    float acc = bc[t];
    for (int k = 0; k < HID; k++) acc += pooled[k] * Wc[k * NOUT + t];
    out[gph * NOUT + t] = acc;
}

extern "C" void kernel_launch(void* const* d_in, const int* in_sizes, int n_in,
                              void* d_out, int out_size, void* d_ws, size_t ws_size,
                              hipStream_t stream) {
    const float* x     = (const float*)d_in[0];
    const int*   ei    = (const int*)d_in[1];
    const int*   batch = (const int*)d_in[3];
    const float* W1    = (const float*)d_in[4];
    const float* b1    = (const float*)d_in[5];
    const float* W2    = (const float*)d_in[6];
    const float* b2    = (const float*)d_in[7];
    const float* Wfc   = (const float*)d_in[8];
    const float* bfc   = (const float*)d_in[9];
    float* out = (float*)d_out;

    const int* src = ei;
    const int* dst = ei + NE;

    char* p = (char*)d_ws;
    auto take = [&](size_t bytes) { char* r = p; p += (bytes + 255) & ~(size_t)255; return r; };
    // zero-group (one memset covers bcnt..psum)
    int*   bcnt = (int*)take((size_t)NBUK * 4);
    int*   cntg = (int*)take((size_t)NG * 4);
    float* psum = (float*)take((size_t)NG * HID * 4);
    size_t zspan = (size_t)((char*)psum + (size_t)NG * HID * 4 - (char*)bcnt);
    int*   boff = (int*)take((size_t)(NBUK + 1) * 4);
    int*   gcur = (int*)take((size_t)NBUK * 4);
    int*   rp   = (int*)take((size_t)(NN + 1) * 4);
    float* dinv = (float*)take((size_t)NN * 4);
    u16*   Wp1  = (u16*)take((size_t)32 * 64 * 8 * 2);
    float* Wc   = (float*)take((size_t)HID * NOUT * 4);
    float* bc   = (float*)take((size_t)NOUT * 4);
    int*   col  = (int*)take((size_t)NE * 4);
    u16*   g    = (u16*)take((size_t)NN * HID * 2);
    u16*   t    = (u16*)take((size_t)NN * HID * 2);
    EdgeT* ebuf = (EdgeT*)g;   // aliased: ebuf (12.8MB) consumed before k_gemm writes g

    hipMemsetAsync(bcnt, 0, zspan, stream);

    k_bhist  <<<NAH, 256, 0, stream>>>(dst, bcnt);
    k_bscan  <<<1, 256, 0, stream>>>(bcnt, boff, gcur, rp + NN);
    k_scatter<<<NSC, 256, 0, stream>>>(src, dst, gcur, ebuf);
    k_bucketc<<<NBUK, 256, 0, stream>>>(ebuf, boff, batch, rp, dinv, cntg, col);
    k_wprep  <<<(2048 + HID * NOUT + NOUT + 255) / 256, 256, 0, stream>>>
             (W1, Wp1, W2, Wfc, b2, bfc, Wc, bc);

    k_gemm   <<<(NN + 63) / 64, 256, 0, stream>>>(x, Wp1, dinv, g);
    k_agg<1> <<<NGRP * 2, 256, 0, stream>>>(g, rp, col, dinv, b1, t, nullptr, nullptr);
    k_agg<2> <<<NGRP * 2, 256, 0, stream>>>(t, rp, col, dinv, nullptr, nullptr, batch, psum);
    k_fc     <<<NG, 64, 0, stream>>>(psum, cntg, Wc, bc, out);
}

// Round 11
// 385.902 us; speedup vs baseline: 4.5281x; 1.1232x over previous
//
#include <hip/hip_runtime.h>
#include <stdint.h>

#define NN   100000
#define NE   1600000
#define NG   512
#define HID  128
#define NOUT 64
#define BK   512
#define NBUK ((NN + BK - 1) / BK)            // 196 dst-buckets of 512
#define AHIST_E 4096
#define NAH  ((NE + AHIST_E - 1) / AHIST_E)  // 391
#define CHUNK 8192
#define NSC  ((NE + CHUNK - 1) / CHUNK)      // 196
#define NGRP ((NN + 3) / 4)                  // node groups of 4

typedef __bf16 bf16_t;
typedef bf16_t bf16x8 __attribute__((ext_vector_type(8)));
typedef float  f32x4  __attribute__((ext_vector_type(4)));
typedef unsigned int u32;
typedef u32 u32x2 __attribute__((ext_vector_type(2)));
typedef u32 u32x4 __attribute__((ext_vector_type(4)));
typedef unsigned short u16;

struct __align__(8) EdgeT { int d, s; };

__device__ __forceinline__ u16 f2b(float f) {
    union { float f; u32 u; } v; v.f = f;
    u32 u = v.u + 0x7fffu + ((v.u >> 16) & 1u);   // RNE
    return (u16)(u >> 16);
}
__device__ __forceinline__ float blo(u32 u) {
    union { u32 u; float f; } v; v.u = u << 16; return v.f;
}
__device__ __forceinline__ float bhi(u32 u) {
    union { u32 u; float f; } v; v.u = u & 0xffff0000u; return v.f;
}

// ---------------- CSR build, bucketed (R6-proven) ----------------
__global__ __launch_bounds__(256) void k_bhist(const int* __restrict__ dst,
                                               int* __restrict__ bcnt) {
    __shared__ int h[NBUK];
    int t = threadIdx.x;
    for (int i = t; i < NBUK; i += 256) h[i] = 0;
    __syncthreads();
    int e0 = blockIdx.x * AHIST_E;
    int e1 = min(NE, e0 + AHIST_E);
    for (int e = e0 + t; e < e1; e += 256) atomicAdd(&h[dst[e] >> 9], 1);
    __syncthreads();
    for (int i = t; i < NBUK; i += 256) if (h[i]) atomicAdd(&bcnt[i], h[i]);
}

__global__ __launch_bounds__(256) void k_bscan(const int* __restrict__ bcnt,
                                               int* __restrict__ boff, int* __restrict__ gcur,
                                               int* __restrict__ rpN) {
    __shared__ int sh[256];
    int t = threadIdx.x;
    int v = (t < NBUK) ? bcnt[t] : 0;
    sh[t] = v; __syncthreads();
    for (int off = 1; off < 256; off <<= 1) {
        int x = (t >= off) ? sh[t - off] : 0;
        __syncthreads();
        sh[t] += x;
        __syncthreads();
    }
    if (t < NBUK) { int b = sh[t] - v; boff[t] = b; gcur[t] = b; }
    if (t == 0) { boff[NBUK] = NE; rpN[0] = NE; }
}

__global__ __launch_bounds__(256) void k_scatter(const int* __restrict__ src,
                                                 const int* __restrict__ dst,
                                                 int* __restrict__ gcur,
                                                 EdgeT* __restrict__ ebuf) {
    __shared__ int hist[NBUK], base[NBUK];
    int t = threadIdx.x;
    for (int i = t; i < NBUK; i += 256) hist[i] = 0;
    __syncthreads();
    int e0 = blockIdx.x * CHUNK;
    int e1 = min(NE, e0 + CHUNK);
    for (int e = e0 + t; e < e1; e += 256) atomicAdd(&hist[dst[e] >> 9], 1);
    __syncthreads();
    for (int i = t; i < NBUK; i += 256) {
        int h = hist[i];
        base[i] = h ? atomicAdd(&gcur[i], h) : 0;
        hist[i] = 0;
    }
    __syncthreads();
    for (int e = e0 + t; e < e1; e += 256) {
        int d = dst[e], bk = d >> 9;
        int r = atomicAdd(&hist[bk], 1);
        EdgeT p; p.d = d; p.s = src[e];
        ebuf[base[bk] + r] = p;
    }
}

__global__ __launch_bounds__(256) void k_bucketc(const EdgeT* __restrict__ ebuf,
                                                 const int* __restrict__ boff,
                                                 const int* __restrict__ batch,
                                                 int* __restrict__ rp, float* __restrict__ dinv,
                                                 int* __restrict__ cntg, int* __restrict__ col) {
    __shared__ int cnt[BK], pos[BK], run[BK], s2[256];
    int b = blockIdx.x, t = threadIdx.x;
    int d0 = b * BK;
    int e0 = boff[b], e1 = boff[b + 1];
    for (int i = t; i < BK; i += 256) { cnt[i] = 0; run[i] = 0; }
    __syncthreads();
    for (int e = e0 + t; e < e1; e += 256) atomicAdd(&cnt[ebuf[e].d - d0], 1);
    __syncthreads();
    for (int i = t; i < BK; i += 256) {
        int v = d0 + i;
        if (v < NN) {
            dinv[v] = rsqrtf((float)(cnt[i] + 1));
            atomicAdd(&cntg[batch[v]], 1);
        }
    }
    int c0 = cnt[2 * t], c1 = cnt[2 * t + 1];
    int s = c0 + c1; s2[t] = s; __syncthreads();
    for (int off = 1; off < 256; off <<= 1) {
        int x = (t >= off) ? s2[t - off] : 0;
        __syncthreads();
        s2[t] += x;
        __syncthreads();
    }
    int bse = s2[t] - s;
    pos[2 * t] = bse; pos[2 * t + 1] = bse + c0;
    __syncthreads();
    for (int i = t; i < BK; i += 256) {
        int v = d0 + i;
        if (v < NN) rp[v] = e0 + pos[i];
    }
    for (int e = e0 + t; e < e1; e += 256) {
        EdgeT p = ebuf[e];
        int i = p.d - d0;
        int r = atomicAdd(&run[i], 1);
        col[e0 + pos[i] + r] = p.s;
    }
}

// ---------------- fused weight prep ----------------
// tid<2048: pack W1 -> Wp1 (8 col-frags, n_global=(l&15)*8+c)
// [2048,10240): Wcp packed bf16 of Wc=W2@Wfc (4 col-frags, n_global=(l&15)*4+c),
//               slot computed directly from (k,n): no Wc materialization.
// [10240,10304): bc = b2 @ Wfc + bfc
__global__ void k_wprep(const float* __restrict__ W1, u16* __restrict__ Wp,
                        const float* __restrict__ W2, const float* __restrict__ Wfc,
                        const float* __restrict__ b2, const float* __restrict__ bfc,
                        u16* __restrict__ Wcp, float* __restrict__ bc) {
    int tid = blockIdx.x * blockDim.x + threadIdx.x;
    if (tid < 2048) {
        int f = tid >> 6, l = tid & 63;
        int c = f >> 2, s = f & 3;
        int n  = (l & 15) * 8 + c;
        int k0 = s * 32 + ((l >> 4) << 3);
#pragma unroll
        for (int j = 0; j < 8; j++) Wp[tid * 8 + j] = f2b(W1[(k0 + j) * HID + n]);
    } else if (tid < 2048 + HID * NOUT) {
        int t2 = tid - 2048;
        int k = t2 >> 6, n = t2 & 63;
        float a = 0.f;
        for (int m = 0; m < HID; m++) a += W2[k * HID + m] * Wfc[m * NOUT + n];
        int s = k >> 5, lh = (k >> 3) & 3, j = k & 7;
        int c = n & 3, l15 = n >> 2;
        int l = (lh << 4) | l15, f = c * 4 + s;
        Wcp[((f * 64 + l) << 3) + j] = f2b(a);
    } else if (tid < 2048 + HID * NOUT + NOUT) {
        int o = tid - 2048 - HID * NOUT;
        float a = bfc[o];
        for (int k = 0; k < HID; k++) a += b2[k] * Wfc[k * NOUT + o];
        bc[o] = a;
    }
}

// ---------------- GEMM1: g = bf16((X @ W1) * dinv[row]), [NN][128] ----------------
__global__ __launch_bounds__(256) void k_gemm(const float* __restrict__ Xf,
                                              const u16* __restrict__ Wp,
                                              const float* __restrict__ dinv,
                                              u16* __restrict__ Gout) {
    int w = threadIdx.x >> 6, l = threadIdx.x & 63;
    int r0  = blockIdx.x * 64 + w * 16;
    int l15 = l & 15, lh = l >> 4;
    int arow = r0 + l15;
    int arc  = (arow < NN) ? arow : (NN - 1);

    f32x4 acc[8];
#pragma unroll
    for (int c = 0; c < 8; c++) acc[c] = (f32x4){0.f, 0.f, 0.f, 0.f};

#pragma unroll
    for (int s = 0; s < 4; s++) {
        int k0 = s * 32 + lh * 8;
        f32x4 p0 = *(const f32x4*)(Xf + (size_t)arc * HID + k0);
        f32x4 p1 = *(const f32x4*)(Xf + (size_t)arc * HID + k0 + 4);
        union { bf16x8 v; u16 h[8]; } au;
#pragma unroll
        for (int j = 0; j < 4; j++) { au.h[j] = f2b(p0[j]); au.h[j + 4] = f2b(p1[j]); }
        bf16x8 a = au.v;
#pragma unroll
        for (int c = 0; c < 8; c++) {
            bf16x8 b = *(const bf16x8*)(Wp + ((c * 4 + s) * 64 + l) * 8);
            acc[c] = __builtin_amdgcn_mfma_f32_16x16x32_bf16(a, b, acc[c], 0, 0, 0);
        }
    }
#pragma unroll
    for (int q = 0; q < 4; q++) {
        int row = r0 + lh * 4 + q;
        if (row < NN) {
            float dv = dinv[row];
            union { u32x4 v; u16 h[8]; } pk;
#pragma unroll
            for (int c = 0; c < 8; c++) pk.h[c] = f2b(acc[c][q] * dv);
            *(u32x4*)(Gout + (size_t)row * HID + l15 * 8) = pk.v;
        }
    }
}

// ---------------- agg1 (R6-proven): T[v] = bf16(dinv*relu(dinv*Sum + b1)) -------
__global__ __launch_bounds__(256) void k_agg1(const u16* __restrict__ g,
                                              const int* __restrict__ rp,
                                              const int* __restrict__ col,
                                              const float* __restrict__ dinv,
                                              const float* __restrict__ bias,
                                              u16* __restrict__ tout) {
    int w = threadIdx.x >> 6, l = threadIdx.x & 63;
    int v = blockIdx.x * 4 + w;
    if (v >= NN) return;
    int f0 = 2 * l;
    const u16* gl = g + f0;

    u32 u = *(const u32*)(gl + (size_t)v * HID);   // self loop
    float a0 = blo(u), a1 = bhi(u);

    int e = rp[v], end = rp[v + 1];
    while (e < end) {
        int m = end - e; if (m > 64) m = 64;
        int ci = col[e + ((l < m) ? l : 0)];
        int j = 0;
        for (; j + 16 <= m; j += 16) {
            u32 uu[16];
#pragma unroll
            for (int k = 0; k < 16; k++) {
                int idx = __shfl(ci, j + k);
                uu[k] = *(const u32*)(gl + (size_t)idx * HID);
            }
#pragma unroll
            for (int k = 0; k < 16; k++) { a0 += blo(uu[k]); a1 += bhi(uu[k]); }
        }
        for (; j + 4 <= m; j += 4) {
            u32 uu[4];
#pragma unroll
            for (int k = 0; k < 4; k++) {
                int idx = __shfl(ci, j + k);
                uu[k] = *(const u32*)(gl + (size_t)idx * HID);
            }
#pragma unroll
            for (int k = 0; k < 4; k++) { a0 += blo(uu[k]); a1 += bhi(uu[k]); }
        }
        if (j < m) {
            int r = m - j;
            u32 uu[3];
#pragma unroll
            for (int k = 0; k < 3; k++) {
                int jk = j + k; int idx = __shfl(ci, (jk < m) ? jk : j);
                uu[k] = *(const u32*)(gl + (size_t)idx * HID);
            }
#pragma unroll
            for (int k = 0; k < 3; k++) {
                float mk = (k < r) ? 1.f : 0.f;
                a0 = fmaf(mk, blo(uu[k]), a0); a1 = fmaf(mk, bhi(uu[k]), a1);
            }
        }
        e += m;
    }

    float dv = dinv[v];
    float o0 = fmaxf(a0 * dv + bias[f0],     0.f) * dv;
    float o1 = fmaxf(a1 * dv + bias[f0 + 1], 0.f) * dv;
    u32 pk = (u32)f2b(o0) | ((u32)f2b(o1) << 16);
    int l15 = l & 15;
    u32 w0 = __shfl(pk, l15 * 4 + 0);
    u32 w1 = __shfl(pk, l15 * 4 + 1);
    u32 w2 = __shfl(pk, l15 * 4 + 2);
    u32 w3 = __shfl(pk, l15 * 4 + 3);
    if (l < 16) {
        u32x4 vv = (u32x4){w0, w1, w2, w3};
        *(u32x4*)(tout + (size_t)v * HID + l * 8) = vv;
    }
}

// ---------------- GEMM2: U = bf16(T @ Wc), [NN][64] (128B rows) ----------------
__global__ __launch_bounds__(256) void k_gemm2(const u16* __restrict__ T,
                                               const u16* __restrict__ Wcp,
                                               u16* __restrict__ U) {
    int w = threadIdx.x >> 6, l = threadIdx.x & 63;
    int r0  = blockIdx.x * 64 + w * 16;
    int l15 = l & 15, lh = l >> 4;
    int arow = r0 + l15;
    int arc  = (arow < NN) ? arow : (NN - 1);

    f32x4 acc[4];
#pragma unroll
    for (int c = 0; c < 4; c++) acc[c] = (f32x4){0.f, 0.f, 0.f, 0.f};

#pragma unroll
    for (int s = 0; s < 4; s++) {
        int k0 = s * 32 + lh * 8;
        bf16x8 a = *(const bf16x8*)(T + (size_t)arc * HID + k0);
#pragma unroll
        for (int c = 0; c < 4; c++) {
            bf16x8 b = *(const bf16x8*)(Wcp + ((c * 4 + s) * 64 + l) * 8);
            acc[c] = __builtin_amdgcn_mfma_f32_16x16x32_bf16(a, b, acc[c], 0, 0, 0);
        }
    }
    // lane l15 owns global cols [4*l15, 4*l15+4) -> 8B store
#pragma unroll
    for (int q = 0; q < 4; q++) {
        int row = r0 + lh * 4 + q;
        if (row < NN) {
            union { u32x2 v; u16 h[4]; } pk;
#pragma unroll
            for (int c = 0; c < 4; c++) pk.h[c] = f2b(acc[c][q]);
            *(u32x2*)(U + (size_t)row * NOUT + l15 * 4) = pk.v;
        }
    }
}

// ---------------- agg2: gather U (128B rows), pool into psum[G][64] ----------------
// Wave = 4 quarters x 16 lanes; one dwordx2 load instruction covers 4 rows
// (16 lanes x 8B per row).  16-block: 4 loads + 4 shfls, 16 rows in flight.
__global__ __launch_bounds__(256) void k_agg2(const u16* __restrict__ U,
                                              const int* __restrict__ rp,
                                              const int* __restrict__ col,
                                              const float* __restrict__ dinv,
                                              const int* __restrict__ batch,
                                              float* __restrict__ psum) {
    int w = threadIdx.x >> 6, l = threadIdx.x & 63;
    int v = blockIdx.x * 4 + w;
    if (v >= NN) return;
    int q = l >> 4, lq = l & 15;
    const u16* Ul = U + 4 * lq;           // lane's 8B within any 128B row

    float a0 = 0.f, a1 = 0.f, a2 = 0.f, a3 = 0.f;

    int e = rp[v], end = rp[v + 1];
    while (e < end) {
        int m = end - e; if (m > 64) m = 64;
        int ci = col[e + ((l < m) ? l : 0)];
        int j = 0;
        for (; j + 16 <= m; j += 16) {
            u32x2 uu[4];
#pragma unroll
            for (int k = 0; k < 4; k++) {
                int idx = __shfl(ci, j + 4 * k + q);
                uu[k] = *(const u32x2*)(Ul + (size_t)idx * NOUT);
            }
#pragma unroll
            for (int k = 0; k < 4; k++) {
                a0 += blo(uu[k].x); a1 += bhi(uu[k].x);
                a2 += blo(uu[k].y); a3 += bhi(uu[k].y);
            }
        }
        for (; j + 4 <= m; j += 4) {
            int idx = __shfl(ci, j + q);
            u32x2 u0 = *(const u32x2*)(Ul + (size_t)idx * NOUT);
            a0 += blo(u0.x); a1 += bhi(u0.x);
            a2 += blo(u0.y); a3 += bhi(u0.y);
        }
        if (j < m) {
            int ok = (j + q < m);
            int idx = __shfl(ci, ok ? (j + q) : j);
            u32x2 u0 = *(const u32x2*)(Ul + (size_t)idx * NOUT);
            float mk = ok ? 1.f : 0.f;
            a0 = fmaf(mk, blo(u0.x), a0); a1 = fmaf(mk, bhi(u0.x), a1);
            a2 = fmaf(mk, blo(u0.y), a2); a3 = fmaf(mk, bhi(u0.y), a3);
        }
        e += m;
    }

    // reduce across quarters (lanes l, l^16, l^32, l^48 share feature slot lq)
    a0 += __shfl_xor(a0, 16); a0 += __shfl_xor(a0, 32);
    a1 += __shfl_xor(a1, 16); a1 += __shfl_xor(a1, 32);
    a2 += __shfl_xor(a2, 16); a2 += __shfl_xor(a2, 32);
    a3 += __shfl_xor(a3, 16); a3 += __shfl_xor(a3, 32);

    // self loop once, post-reduce (all quarters read identical values)
    u32x2 su = *(const u32x2*)(Ul + (size_t)v * NOUT);
    a0 += blo(su.x); a1 += bhi(su.x); a2 += blo(su.y); a3 += bhi(su.y);

    if (q == 0) {
        float dv = dinv[v];
        float* ps = psum + (size_t)batch[v] * NOUT + 4 * lq;
        atomicAdd(ps + 0, a0 * dv);
        atomicAdd(ps + 1, a1 * dv);
        atomicAdd(ps + 2, a2 * dv);
        atomicAdd(ps + 3, a3 * dv);
    }
}

// ---------------- final: out[g][o] = psum[g][o]/cnt + bc[o] ----------------
__global__ __launch_bounds__(256) void k_fc(const float* __restrict__ psum,
                                            const int* __restrict__ cntg,
                                            const float* __restrict__ bc,
                                            float* __restrict__ out) {
    int tid = blockIdx.x * blockDim.x + threadIdx.x;
    if (tid < NG * NOUT) {
        int gph = tid >> 6, o = tid & 63;
        float inv = 1.f / fmaxf((float)cntg[gph], 1.f);
        out[tid] = psum[tid] * inv + bc[o];
    }
}

extern "C" void kernel_launch(void* const* d_in, const int* in_sizes, int n_in,
                              void* d_out, int out_size, void* d_ws, size_t ws_size,
                              hipStream_t stream) {
    const float* x     = (const float*)d_in[0];
    const int*   ei    = (const int*)d_in[1];
    const int*   batch = (const int*)d_in[3];
    const float* W1    = (const float*)d_in[4];
    const float* b1    = (const float*)d_in[5];
    const float* W2    = (const float*)d_in[6];
    const float* b2    = (const float*)d_in[7];
    const float* Wfc   = (const float*)d_in[8];
    const float* bfc   = (const float*)d_in[9];
    float* out = (float*)d_out;

    const int* src = ei;
    const int* dst = ei + NE;

    char* p = (char*)d_ws;
    auto take = [&](size_t bytes) { char* r = p; p += (bytes + 255) & ~(size_t)255; return r; };
    // zero-group (one memset covers bcnt..psum)
    int*   bcnt = (int*)take((size_t)NBUK * 4);
    int*   cntg = (int*)take((size_t)NG * 4);
    float* psum = (float*)take((size_t)NG * NOUT * 4);
    size_t zspan = (size_t)((char*)psum + (size_t)NG * NOUT * 4 - (char*)bcnt);
    int*   boff = (int*)take((size_t)(NBUK + 1) * 4);
    int*   gcur = (int*)take((size_t)NBUK * 4);
    int*   rp   = (int*)take((size_t)(NN + 1) * 4);
    float* dinv = (float*)take((size_t)NN * 4);
    u16*   Wp1  = (u16*)take((size_t)32 * 64 * 8 * 2);
    u16*   Wcp  = (u16*)take((size_t)16 * 64 * 8 * 2);
    float* bc   = (float*)take((size_t)NOUT * 4);
    int*   col  = (int*)take((size_t)NE * 4);
    u16*   g    = (u16*)take((size_t)NN * HID * 2);
    u16*   t    = (u16*)take((size_t)NN * HID * 2);
    u16*   U    = (u16*)take((size_t)NN * NOUT * 2);
    EdgeT* ebuf = (EdgeT*)g;   // aliased: ebuf consumed by k_bucketc before k_gemm writes g

    hipMemsetAsync(bcnt, 0, zspan, stream);

    k_bhist  <<<NAH, 256, 0, stream>>>(dst, bcnt);
    k_bscan  <<<1, 256, 0, stream>>>(bcnt, boff, gcur, rp + NN);
    k_scatter<<<NSC, 256, 0, stream>>>(src, dst, gcur, ebuf);
    k_bucketc<<<NBUK, 256, 0, stream>>>(ebuf, boff, batch, rp, dinv, cntg, col);
    k_wprep  <<<(2048 + HID * NOUT + NOUT + 255) / 256, 256, 0, stream>>>
             (W1, Wp1, W2, Wfc, b2, bfc, Wcp, bc);

    k_gemm   <<<(NN + 63) / 64, 256, 0, stream>>>(x, Wp1, dinv, g);
    k_agg1   <<<NGRP, 256, 0, stream>>>(g, rp, col, dinv, b1, t);
    k_gemm2  <<<(NN + 63) / 64, 256, 0, stream>>>(t, Wcp, U);
    k_agg2   <<<NGRP, 256, 0, stream>>>(U, rp, col, dinv, batch, psum);
    k_fc     <<<(NG * NOUT + 255) / 256, 256, 0, stream>>>(psum, cntg, bc, out);
}

// Round 12
// 344.979 us; speedup vs baseline: 5.0652x; 1.1186x over previous
//
#include <hip/hip_runtime.h>
#include <stdint.h>

#define NN   100000
#define NE   1600000
#define NG   512
#define HID  128
#define NOUT 64
#define BK   512
#define NBUK ((NN + BK - 1) / BK)            // 196 dst-buckets of 512
#define AHIST_E 4096
#define NAH  ((NE + AHIST_E - 1) / AHIST_E)  // 391
#define CHUNK 8192
#define NSC  ((NE + CHUNK - 1) / CHUNK)      // 196
#define NGRP ((NN + 3) / 4)                  // node groups of 4

typedef __bf16 bf16_t;
typedef bf16_t bf16x8 __attribute__((ext_vector_type(8)));
typedef float  f32x4  __attribute__((ext_vector_type(4)));
typedef unsigned int u32;
typedef u32 u32x2 __attribute__((ext_vector_type(2)));
typedef u32 u32x4 __attribute__((ext_vector_type(4)));
typedef unsigned short u16;

struct __align__(8) EdgeT { int d, s; };

__device__ __forceinline__ u16 f2b(float f) {
    union { float f; u32 u; } v; v.f = f;
    u32 u = v.u + 0x7fffu + ((v.u >> 16) & 1u);   // RNE
    return (u16)(u >> 16);
}
__device__ __forceinline__ float blo(u32 u) {
    union { u32 u; float f; } v; v.u = u << 16; return v.f;
}
__device__ __forceinline__ float bhi(u32 u) {
    union { u32 u; float f; } v; v.u = u & 0xffff0000u; return v.f;
}

// ---------------- CSR build, bucketed (R6-proven) ----------------
__global__ __launch_bounds__(256) void k_bhist(const int* __restrict__ dst,
                                               int* __restrict__ bcnt) {
    __shared__ int h[NBUK];
    int t = threadIdx.x;
    for (int i = t; i < NBUK; i += 256) h[i] = 0;
    __syncthreads();
    int e0 = blockIdx.x * AHIST_E;
    int e1 = min(NE, e0 + AHIST_E);
    for (int e = e0 + t; e < e1; e += 256) atomicAdd(&h[dst[e] >> 9], 1);
    __syncthreads();
    for (int i = t; i < NBUK; i += 256) if (h[i]) atomicAdd(&bcnt[i], h[i]);
}

__global__ __launch_bounds__(256) void k_bscan(const int* __restrict__ bcnt,
                                               int* __restrict__ boff, int* __restrict__ gcur,
                                               int* __restrict__ rpN) {
    __shared__ int sh[256];
    int t = threadIdx.x;
    int v = (t < NBUK) ? bcnt[t] : 0;
    sh[t] = v; __syncthreads();
    for (int off = 1; off < 256; off <<= 1) {
        int x = (t >= off) ? sh[t - off] : 0;
        __syncthreads();
        sh[t] += x;
        __syncthreads();
    }
    if (t < NBUK) { int b = sh[t] - v; boff[t] = b; gcur[t] = b; }
    if (t == 0) { boff[NBUK] = NE; rpN[0] = NE; }
}

__global__ __launch_bounds__(256) void k_scatter(const int* __restrict__ src,
                                                 const int* __restrict__ dst,
                                                 int* __restrict__ gcur,
                                                 EdgeT* __restrict__ ebuf) {
    __shared__ int hist[NBUK], base[NBUK];
    int t = threadIdx.x;
    for (int i = t; i < NBUK; i += 256) hist[i] = 0;
    __syncthreads();
    int e0 = blockIdx.x * CHUNK;
    int e1 = min(NE, e0 + CHUNK);
    for (int e = e0 + t; e < e1; e += 256) atomicAdd(&hist[dst[e] >> 9], 1);
    __syncthreads();
    for (int i = t; i < NBUK; i += 256) {
        int h = hist[i];
        base[i] = h ? atomicAdd(&gcur[i], h) : 0;
        hist[i] = 0;
    }
    __syncthreads();
    for (int e = e0 + t; e < e1; e += 256) {
        int d = dst[e], bk = d >> 9;
        int r = atomicAdd(&hist[bk], 1);
        EdgeT p; p.d = d; p.s = src[e];
        ebuf[base[bk] + r] = p;
    }
}

__global__ __launch_bounds__(256) void k_bucketc(const EdgeT* __restrict__ ebuf,
                                                 const int* __restrict__ boff,
                                                 const int* __restrict__ batch,
                                                 int* __restrict__ rp, float* __restrict__ dinv,
                                                 int* __restrict__ cntg, int* __restrict__ col) {
    __shared__ int cnt[BK], pos[BK], run[BK], s2[256];
    int b = blockIdx.x, t = threadIdx.x;
    int d0 = b * BK;
    int e0 = boff[b], e1 = boff[b + 1];
    for (int i = t; i < BK; i += 256) { cnt[i] = 0; run[i] = 0; }
    __syncthreads();
    for (int e = e0 + t; e < e1; e += 256) atomicAdd(&cnt[ebuf[e].d - d0], 1);
    __syncthreads();
    for (int i = t; i < BK; i += 256) {
        int v = d0 + i;
        if (v < NN) {
            dinv[v] = rsqrtf((float)(cnt[i] + 1));
            atomicAdd(&cntg[batch[v]], 1);
        }
    }
    int c0 = cnt[2 * t], c1 = cnt[2 * t + 1];
    int s = c0 + c1; s2[t] = s; __syncthreads();
    for (int off = 1; off < 256; off <<= 1) {
        int x = (t >= off) ? s2[t - off] : 0;
        __syncthreads();
        s2[t] += x;
        __syncthreads();
    }
    int bse = s2[t] - s;
    pos[2 * t] = bse; pos[2 * t + 1] = bse + c0;
    __syncthreads();
    for (int i = t; i < BK; i += 256) {
        int v = d0 + i;
        if (v < NN) rp[v] = e0 + pos[i];
    }
    for (int e = e0 + t; e < e1; e += 256) {
        EdgeT p = ebuf[e];
        int i = p.d - d0;
        int r = atomicAdd(&run[i], 1);
        col[e0 + pos[i] + r] = p.s;
    }
}

// ---------------- fused weight prep ----------------
__global__ void k_wprep(const float* __restrict__ W1, u16* __restrict__ Wp,
                        const float* __restrict__ W2, const float* __restrict__ Wfc,
                        const float* __restrict__ b2, const float* __restrict__ bfc,
                        u16* __restrict__ Wcp, float* __restrict__ bc) {
    int tid = blockIdx.x * blockDim.x + threadIdx.x;
    if (tid < 2048) {
        int f = tid >> 6, l = tid & 63;
        int c = f >> 2, s = f & 3;
        int n  = (l & 15) * 8 + c;
        int k0 = s * 32 + ((l >> 4) << 3);
#pragma unroll
        for (int j = 0; j < 8; j++) Wp[tid * 8 + j] = f2b(W1[(k0 + j) * HID + n]);
    } else if (tid < 2048 + HID * NOUT) {
        int t2 = tid - 2048;
        int k = t2 >> 6, n = t2 & 63;
        float a = 0.f;
        for (int m = 0; m < HID; m++) a += W2[k * HID + m] * Wfc[m * NOUT + n];
        int s = k >> 5, lh = (k >> 3) & 3, j = k & 7;
        int c = n & 3, l15 = n >> 2;
        int l = (lh << 4) | l15, f = c * 4 + s;
        Wcp[((f * 64 + l) << 3) + j] = f2b(a);
    } else if (tid < 2048 + HID * NOUT + NOUT) {
        int o = tid - 2048 - HID * NOUT;
        float a = bfc[o];
        for (int k = 0; k < HID; k++) a += b2[k] * Wfc[k * NOUT + o];
        bc[o] = a;
    }
}

// ---------------- GEMM1: g = bf16((X @ W1) * dinv[row]), [NN][128] ----------------
__global__ __launch_bounds__(256) void k_gemm(const float* __restrict__ Xf,
                                              const u16* __restrict__ Wp,
                                              const float* __restrict__ dinv,
                                              u16* __restrict__ Gout) {
    int w = threadIdx.x >> 6, l = threadIdx.x & 63;
    int r0  = blockIdx.x * 64 + w * 16;
    int l15 = l & 15, lh = l >> 4;
    int arow = r0 + l15;
    int arc  = (arow < NN) ? arow : (NN - 1);

    f32x4 acc[8];
#pragma unroll
    for (int c = 0; c < 8; c++) acc[c] = (f32x4){0.f, 0.f, 0.f, 0.f};

#pragma unroll
    for (int s = 0; s < 4; s++) {
        int k0 = s * 32 + lh * 8;
        f32x4 p0 = *(const f32x4*)(Xf + (size_t)arc * HID + k0);
        f32x4 p1 = *(const f32x4*)(Xf + (size_t)arc * HID + k0 + 4);
        union { bf16x8 v; u16 h[8]; } au;
#pragma unroll
        for (int j = 0; j < 4; j++) { au.h[j] = f2b(p0[j]); au.h[j + 4] = f2b(p1[j]); }
        bf16x8 a = au.v;
#pragma unroll
        for (int c = 0; c < 8; c++) {
            bf16x8 b = *(const bf16x8*)(Wp + ((c * 4 + s) * 64 + l) * 8);
            acc[c] = __builtin_amdgcn_mfma_f32_16x16x32_bf16(a, b, acc[c], 0, 0, 0);
        }
    }
#pragma unroll
    for (int q = 0; q < 4; q++) {
        int row = r0 + lh * 4 + q;
        if (row < NN) {
            float dv = dinv[row];
            union { u32x4 v; u16 h[8]; } pk;
#pragma unroll
            for (int c = 0; c < 8; c++) pk.h[c] = f2b(acc[c][q] * dv);
            *(u32x4*)(Gout + (size_t)row * HID + l15 * 8) = pk.v;
        }
    }
}

// ---------------- agg1 (R6-proven): T[v] = bf16(dinv*relu(dinv*Sum + b1)) -------
__global__ __launch_bounds__(256) void k_agg1(const u16* __restrict__ g,
                                              const int* __restrict__ rp,
                                              const int* __restrict__ col,
                                              const float* __restrict__ dinv,
                                              const float* __restrict__ bias,
                                              u16* __restrict__ tout) {
    int w = threadIdx.x >> 6, l = threadIdx.x & 63;
    int v = blockIdx.x * 4 + w;
    if (v >= NN) return;
    int f0 = 2 * l;
    const u16* gl = g + f0;

    u32 u = *(const u32*)(gl + (size_t)v * HID);   // self loop
    float a0 = blo(u), a1 = bhi(u);

    int e = rp[v], end = rp[v + 1];
    while (e < end) {
        int m = end - e; if (m > 64) m = 64;
        int ci = col[e + ((l < m) ? l : 0)];
        int j = 0;
        for (; j + 16 <= m; j += 16) {
            u32 uu[16];
#pragma unroll
            for (int k = 0; k < 16; k++) {
                int idx = __shfl(ci, j + k);
                uu[k] = *(const u32*)(gl + (size_t)idx * HID);
            }
#pragma unroll
            for (int k = 0; k < 16; k++) { a0 += blo(uu[k]); a1 += bhi(uu[k]); }
        }
        for (; j + 4 <= m; j += 4) {
            u32 uu[4];
#pragma unroll
            for (int k = 0; k < 4; k++) {
                int idx = __shfl(ci, j + k);
                uu[k] = *(const u32*)(gl + (size_t)idx * HID);
            }
#pragma unroll
            for (int k = 0; k < 4; k++) { a0 += blo(uu[k]); a1 += bhi(uu[k]); }
        }
        if (j < m) {
            int r = m - j;
            u32 uu[3];
#pragma unroll
            for (int k = 0; k < 3; k++) {
                int jk = j + k; int idx = __shfl(ci, (jk < m) ? jk : j);
                uu[k] = *(const u32*)(gl + (size_t)idx * HID);
            }
#pragma unroll
            for (int k = 0; k < 3; k++) {
                float mk = (k < r) ? 1.f : 0.f;
                a0 = fmaf(mk, blo(uu[k]), a0); a1 = fmaf(mk, bhi(uu[k]), a1);
            }
        }
        e += m;
    }

    float dv = dinv[v];
    float o0 = fmaxf(a0 * dv + bias[f0],     0.f) * dv;
    float o1 = fmaxf(a1 * dv + bias[f0 + 1], 0.f) * dv;
    u32 pk = (u32)f2b(o0) | ((u32)f2b(o1) << 16);
    int l15 = l & 15;
    u32 w0 = __shfl(pk, l15 * 4 + 0);
    u32 w1 = __shfl(pk, l15 * 4 + 1);
    u32 w2 = __shfl(pk, l15 * 4 + 2);
    u32 w3 = __shfl(pk, l15 * 4 + 3);
    if (l < 16) {
        u32x4 vv = (u32x4){w0, w1, w2, w3};
        *(u32x4*)(tout + (size_t)v * HID + l * 8) = vv;
    }
}

// ---------------- GEMM2: U = bf16(T @ Wc), [NN][64] (128B rows) ----------------
__global__ __launch_bounds__(256) void k_gemm2(const u16* __restrict__ T,
                                               const u16* __restrict__ Wcp,
                                               u16* __restrict__ U) {
    int w = threadIdx.x >> 6, l = threadIdx.x & 63;
    int r0  = blockIdx.x * 64 + w * 16;
    int l15 = l & 15, lh = l >> 4;
    int arow = r0 + l15;
    int arc  = (arow < NN) ? arow : (NN - 1);

    f32x4 acc[4];
#pragma unroll
    for (int c = 0; c < 4; c++) acc[c] = (f32x4){0.f, 0.f, 0.f, 0.f};

#pragma unroll
    for (int s = 0; s < 4; s++) {
        int k0 = s * 32 + lh * 8;
        bf16x8 a = *(const bf16x8*)(T + (size_t)arc * HID + k0);
#pragma unroll
        for (int c = 0; c < 4; c++) {
            bf16x8 b = *(const bf16x8*)(Wcp + ((c * 4 + s) * 64 + l) * 8);
            acc[c] = __builtin_amdgcn_mfma_f32_16x16x32_bf16(a, b, acc[c], 0, 0, 0);
        }
    }
#pragma unroll
    for (int q = 0; q < 4; q++) {
        int row = r0 + lh * 4 + q;
        if (row < NN) {
            union { u32x2 v; u16 h[4]; } pk;
#pragma unroll
            for (int c = 0; c < 4; c++) pk.h[c] = f2b(acc[c][q]);
            *(u32x2*)(U + (size_t)row * NOUT + l15 * 4) = pk.v;
        }
    }
}

// ---------------- agg2: two nodes per wave, 16 loads in flight ----------------
// Lanes 0-31 walk node A's edges, 32-63 node B's; each half covers a full
// 128B U-row (32 lanes x 4B).  Uniform max-loop keeps the wave convergent:
// exhausted half re-reads its last row (L1 hit) with zero mask.
__global__ __launch_bounds__(256) void k_agg2(const u16* __restrict__ U,
                                              const int* __restrict__ rp,
                                              const int* __restrict__ col,
                                              const float* __restrict__ dinv,
                                              const int* __restrict__ batch,
                                              float* __restrict__ psum) {
    int w = threadIdx.x >> 6, l = threadIdx.x & 63;
    int half = l >> 5, lf = l & 31;
    int v = blockIdx.x * 8 + w * 2 + half;      // NN % 8 == 0: always valid
    const u16* Ul = U + 2 * lf;                  // lane's 4B within any 128B row
    int hb = half << 5;

    float a0 = 0.f, a1 = 0.f;
    int e = rp[v], end = rp[v + 1];
    int rem = end - e;
    int remM = max(rem, __shfl_xor(rem, 32));    // wave-uniform

    while (remM > 0) {
        int m  = (rem < 32) ? rem : 32;          // per half (can be 0)
        int mM = (remM < 32) ? remM : 32;        // uniform
        int ce = e + ((lf < m) ? lf : 0);
        ce = (ce < NE) ? ce : (NE - 1);
        int ci = col[ce];
        int j = 0;
        for (; j + 16 <= mM; j += 16) {
            u32 uu[16]; float mk[16];
#pragma unroll
            for (int k = 0; k < 16; k++) {
                int jk = j + k;
                int jc = (jk < m) ? jk : ((m > 0) ? m - 1 : 0);
                int idx = __shfl(ci, hb | jc);
                if (m == 0) idx = v;
                uu[k] = *(const u32*)(Ul + (size_t)idx * NOUT);
                mk[k] = (jk < m) ? 1.f : 0.f;
            }
#pragma unroll
            for (int k = 0; k < 16; k++) {
                a0 = fmaf(mk[k], blo(uu[k]), a0);
                a1 = fmaf(mk[k], bhi(uu[k]), a1);
            }
        }
        for (; j + 4 <= mM; j += 4) {
            u32 uu[4]; float mk[4];
#pragma unroll
            for (int k = 0; k < 4; k++) {
                int jk = j + k;
                int jc = (jk < m) ? jk : ((m > 0) ? m - 1 : 0);
                int idx = __shfl(ci, hb | jc);
                if (m == 0) idx = v;
                uu[k] = *(const u32*)(Ul + (size_t)idx * NOUT);
                mk[k] = (jk < m) ? 1.f : 0.f;
            }
#pragma unroll
            for (int k = 0; k < 4; k++) {
                a0 = fmaf(mk[k], blo(uu[k]), a0);
                a1 = fmaf(mk[k], bhi(uu[k]), a1);
            }
        }
        if (j < mM) {
#pragma unroll
            for (int k = 0; k < 3; k++) {
                int jk = j + k;
                int jc = (jk < m) ? jk : ((m > 0) ? m - 1 : 0);
                int idx = __shfl(ci, hb | jc);
                if (m == 0) idx = v;
                u32 u0 = *(const u32*)(Ul + (size_t)idx * NOUT);
                float mkk = (jk < m) ? 1.f : 0.f;
                a0 = fmaf(mkk, blo(u0), a0);
                a1 = fmaf(mkk, bhi(u0), a1);
            }
        }
        e += m;
        rem = end - e;
        remM = max(rem, __shfl_xor(rem, 32));
    }

    // self loop
    u32 su = *(const u32*)(Ul + (size_t)v * NOUT);
    a0 += blo(su); a1 += bhi(su);

    float dv = dinv[v];
    float* ps = psum + (size_t)batch[v] * NOUT + 2 * lf;
    atomicAdd(ps + 0, a0 * dv);
    atomicAdd(ps + 1, a1 * dv);
}

// ---------------- final: out[g][o] = psum[g][o]/cnt + bc[o] ----------------
__global__ __launch_bounds__(256) void k_fc(const float* __restrict__ psum,
                                            const int* __restrict__ cntg,
                                            const float* __restrict__ bc,
                                            float* __restrict__ out) {
    int tid = blockIdx.x * blockDim.x + threadIdx.x;
    if (tid < NG * NOUT) {
        int gph = tid >> 6, o = tid & 63;
        float inv = 1.f / fmaxf((float)cntg[gph], 1.f);
        out[tid] = psum[tid] * inv + bc[o];
    }
}

extern "C" void kernel_launch(void* const* d_in, const int* in_sizes, int n_in,
                              void* d_out, int out_size, void* d_ws, size_t ws_size,
                              hipStream_t stream) {
    const float* x     = (const float*)d_in[0];
    const int*   ei    = (const int*)d_in[1];
    const int*   batch = (const int*)d_in[3];
    const float* W1    = (const float*)d_in[4];
    const float* b1    = (const float*)d_in[5];
    const float* W2    = (const float*)d_in[6];
    const float* b2    = (const float*)d_in[7];
    const float* Wfc   = (const float*)d_in[8];
    const float* bfc   = (const float*)d_in[9];
    float* out = (float*)d_out;

    const int* src = ei;
    const int* dst = ei + NE;

    char* p = (char*)d_ws;
    auto take = [&](size_t bytes) { char* r = p; p += (bytes + 255) & ~(size_t)255; return r; };
    // zero-group (one memset covers bcnt..psum)
    int*   bcnt = (int*)take((size_t)NBUK * 4);
    int*   cntg = (int*)take((size_t)NG * 4);
    float* psum = (float*)take((size_t)NG * NOUT * 4);
    size_t zspan = (size_t)((char*)psum + (size_t)NG * NOUT * 4 - (char*)bcnt);
    int*   boff = (int*)take((size_t)(NBUK + 1) * 4);
    int*   gcur = (int*)take((size_t)NBUK * 4);
    int*   rp   = (int*)take((size_t)(NN + 1) * 4);
    float* dinv = (float*)take((size_t)NN * 4);
    u16*   Wp1  = (u16*)take((size_t)32 * 64 * 8 * 2);
    u16*   Wcp  = (u16*)take((size_t)16 * 64 * 8 * 2);
    float* bc   = (float*)take((size_t)NOUT * 4);
    int*   col  = (int*)take((size_t)NE * 4);
    u16*   g    = (u16*)take((size_t)NN * HID * 2);
    u16*   t    = (u16*)take((size_t)NN * HID * 2);
    u16*   U    = (u16*)take((size_t)NN * NOUT * 2);
    EdgeT* ebuf = (EdgeT*)g;   // aliased: ebuf consumed by k_bucketc before k_gemm writes g

    hipMemsetAsync(bcnt, 0, zspan, stream);

    k_bhist  <<<NAH, 256, 0, stream>>>(dst, bcnt);
    k_bscan  <<<1, 256, 0, stream>>>(bcnt, boff, gcur, rp + NN);
    k_scatter<<<NSC, 256, 0, stream>>>(src, dst, gcur, ebuf);
    k_bucketc<<<NBUK, 256, 0, stream>>>(ebuf, boff, batch, rp, dinv, cntg, col);
    k_wprep  <<<(2048 + HID * NOUT + NOUT + 255) / 256, 256, 0, stream>>>
             (W1, Wp1, W2, Wfc, b2, bfc, Wcp, bc);

    k_gemm   <<<(NN + 63) / 64, 256, 0, stream>>>(x, Wp1, dinv, g);
    k_agg1   <<<NGRP, 256, 0, stream>>>(g, rp, col, dinv, b1, t);
    k_gemm2  <<<(NN + 63) / 64, 256, 0, stream>>>(t, Wcp, U);
    k_agg2   <<<NN / 8, 256, 0, stream>>>(U, rp, col, dinv, batch, psum);
    k_fc     <<<(NG * NOUT + 255) / 256, 256, 0, stream>>>(psum, cntg, bc, out);
}